// Round 8
// baseline (689.326 us; speedup 1.0000x reference)
//
#include <hip/hip_runtime.h>
#include <hip/hip_bf16.h>

#define B_ 2
#define N_ 384
#define D_ 128
#define LAT_ 256
#define NPOS_ 33
#define ROWS_ (B_*N_)   // 768
#define NT_ 64          // n-rows per attn iteration
#define ITERS_ (N_/NT_) // 6

typedef __attribute__((ext_vector_type(8))) short bf16x8;
typedef __attribute__((ext_vector_type(4))) float f32x4;

#define MFMA(a,b,c) __builtin_amdgcn_mfma_f32_16x16x32_bf16((a),(b),(c),0,0,0)

__device__ __forceinline__ unsigned short f2bf(float x) {
    unsigned int u = __float_as_uint(x);
    u += 0x7FFFu + ((u >> 16) & 1u);   // round-to-nearest-even
    return (unsigned short)(u >> 16);
}
__device__ __forceinline__ float bf2f(unsigned short u) {
    return __uint_as_float(((unsigned int)u) << 16);
}

__device__ __forceinline__ float bn_apply(float x, const float* stats, const float* gam,
                                          const float* bet, int d) {
    float s  = stats[d], sq = stats[128 + d];
    float mean = s * (1.f/ROWS_);
    float var  = sq * (1.f/ROWS_) - mean*mean;
    return (x - mean) * rsqrtf(var + 1e-5f) * gam[d] + bet[d];
}

// ---------------- F-feature precompute: gF[n][64] bf16, swizzled, zero-padded ----------------
// Features: q0=1; q1..3 = 4*xyz[n][j]; q=4+6fi+2j = cos(fr*4x), +1 = sin(fr*4x); q>=34 = 0.
__global__ __launch_bounds__(256) void fprep_kernel(const float* __restrict__ xyz,
                                                    unsigned short* __restrict__ gF) {
    int i = blockIdx.x*256 + threadIdx.x;      // over ROWS_*64
    if (i >= ROWS_*64) return;
    int n = i >> 6, q = i & 63;
    float val;
    if (q == 0) val = 1.f;
    else if (q < 4) val = 4.f*xyz[n*3 + (q-1)];
    else if (q < 34) {
        int u = q-4, fi = u/6, rem = u - fi*6, j = rem >> 1;
        const float fr = fi==0?1.f:(fi==1?8.75f:(fi==2?16.5f:(fi==3?24.25f:32.f)));
        float a = fr*4.f*xyz[n*3+j];
        val = (rem & 1) ? __sinf(a) : __cosf(a);
    } else val = 0.f;
    gF[n*64 + (q ^ ((n & 7) << 3))] = f2bf(val);
}

// ---------------- encode ----------------
__global__ __launch_bounds__(256) void enc_kernel(const float* __restrict__ feats,
                           const float* __restrict__ W,
                           const float* __restrict__ bias,
                           float* __restrict__ f) {
    int i = blockIdx.x*256 + threadIdx.x;
    if (i >= ROWS_*D_) return;
    int r = i >> 7, d = i & 127;
    f[i] = feats[r]*W[d] + bias[d];
}

// ---------------- qkv: 4 rows/block, bf16 K/V out ----------------
__global__ __launch_bounds__(128) void qkv_kernel(const float* __restrict__ graw,
    const float* __restrict__ stats, const float* __restrict__ gam, const float* __restrict__ bet,
    int use_stats,
    const float* __restrict__ Wq, const float* __restrict__ Wk, const float* __restrict__ Wv,
    float* __restrict__ q, unsigned short* __restrict__ k16, unsigned short* __restrict__ v16) {
    __shared__ float rows[4][D_];
    const int r0 = blockIdx.x*4, d = threadIdx.x;
    #pragma unroll
    for (int rr = 0; rr < 4; ++rr) {
        float x = graw[(r0+rr)*D_ + d];
        if (use_stats) x = bn_apply(x, stats, gam, bet, d);
        rows[rr][d] = x;
    }
    __syncthreads();
    float aq[4] = {0,0,0,0}, ak[4] = {0,0,0,0}, av[4] = {0,0,0,0};
    #pragma unroll 4
    for (int e4 = 0; e4 < D_/4; ++e4) {
        float4 wq = *(const float4*)(Wq + d*D_ + e4*4);
        float4 wk = *(const float4*)(Wk + d*D_ + e4*4);
        float4 wv = *(const float4*)(Wv + d*D_ + e4*4);
        #pragma unroll
        for (int rr = 0; rr < 4; ++rr) {
            float4 x = *(const float4*)&rows[rr][e4*4];
            aq[rr] += wq.x*x.x + wq.y*x.y + wq.z*x.z + wq.w*x.w;
            ak[rr] += wk.x*x.x + wk.y*x.y + wk.z*x.z + wk.w*x.w;
            av[rr] += wv.x*x.x + wv.y*x.y + wv.z*x.z + wv.w*x.w;
        }
    }
    #pragma unroll
    for (int rr = 0; rr < 4; ++rr) {
        q[(r0+rr)*D_ + d]   = aq[rr];
        k16[(r0+rr)*D_ + d] = f2bf(ak[rr]);
        v16[(r0+rr)*D_ + d] = f2bf(av[rr]);
    }
}

// ---------------- MFMA attention, factorized pos, 2 barriers/iter ----------------
// 512 thr = 8 waves: rb2 = w>>2 (32-row n-half), ct0 = (w&3)*2 (two 16-d tiles).
// A: [stage F(it+1), loadK(it+1), loadV(it)] Wg1 GEMM sX->sH | bar
// B: Wg2 GEMM sH -> exp/accum(vreg,pos(it)); posGEMM sF@Gamma -> pos(it+1); edges(kreg)->sX | bar
__global__ __launch_bounds__(512) void attn_mfma_kernel(
    const float* __restrict__ xyz, const float* __restrict__ graw,
    const float* __restrict__ stats_in, const float* __restrict__ gam_in,
    const float* __restrict__ bet_in, int use_stats,
    const float* __restrict__ qb,
    const unsigned short* __restrict__ kb, const unsigned short* __restrict__ vb,
    const unsigned short* __restrict__ gF,
    const float* __restrict__ Wpe, const float* __restrict__ bpe,
    const float* __restrict__ Wg1, const float* __restrict__ bg1,
    const float* __restrict__ Wg2, const float* __restrict__ bg2,
    float* __restrict__ gout, float* __restrict__ stats_out)
{
    __shared__ unsigned short sF[NT_*64];    // F features bf16, swizzled (8KB)
    __shared__ unsigned short sX[NT_*128];   // edges bf16, swizzled (16KB)
    __shared__ unsigned short sH[NT_*128];   // h bf16, swizzled (16KB)
    __shared__ float sRed[4*128];

    const int t   = threadIdx.x;
    const int w   = t >> 6;
    const int l   = t & 63;
    const int lr  = l & 15;
    const int lg  = l >> 4;
    const int rb2 = w >> 2;
    const int ct0 = (w & 3) * 2;

    const int row  = blockIdx.x;
    const int b    = row / N_;
    const int brow = b * N_;

    // ---- issue tile-0 staging + K(0) early (hidden under prologue) ----
    uint4 fst = *(const uint4*)(gF + (size_t)brow*64 + t*8);

    float kreg[2][2][4], vreg[2][2][4];
    auto loadK = [&](int n0) {
        #pragma unroll
        for (int rt = 0; rt < 2; ++rt)
        #pragma unroll
        for (int ct = 0; ct < 2; ++ct) {
            const int d = (ct0 + ct)*16 + lr;
            #pragma unroll
            for (int r = 0; r < 4; ++r) {
                const int rr = rb2*32 + rt*16 + lg*4 + r;
                kreg[rt][ct][r] = bf2f(kb[(brow + n0 + rr)*D_ + d]);
            }
        }
    };
    auto loadV = [&](int n0) {
        #pragma unroll
        for (int rt = 0; rt < 2; ++rt)
        #pragma unroll
        for (int ct = 0; ct < 2; ++ct) {
            const int d = (ct0 + ct)*16 + lr;
            #pragma unroll
            for (int r = 0; r < 4; ++r) {
                const int rr = rb2*32 + rt*16 + lg*4 + r;
                vreg[rt][ct][r] = bf2f(vb[(brow + n0 + rr)*D_ + d]);
            }
        }
    };
    loadK(0);

    // ---- prologue: register B-fragments; Gamma built from Wpe + per-m trig ----
    bf16x8 bWg1[2][4], bWg2[2][4], bG[2][2];
    float  bg1_c[2], bg2_c[2], q_c[2];

    const float xm0 = 4.f*xyz[row*3+0];
    const float xm1 = 4.f*xyz[row*3+1];
    const float xm2 = 4.f*xyz[row*3+2];

    #pragma unroll
    for (int ct = 0; ct < 2; ++ct) {
        const int dout = (ct0 + ct) * 16 + lr;
        #pragma unroll
        for (int kt = 0; kt < 4; ++kt) {
            const float* p1 = Wg1 + dout * D_ + kt * 32 + lg * 8;
            const float* p2 = Wg2 + dout * D_ + kt * 32 + lg * 8;
            float4 a0 = *(const float4*)(p1);
            float4 a1 = *(const float4*)(p1 + 4);
            float4 c0 = *(const float4*)(p2);
            float4 c1 = *(const float4*)(p2 + 4);
            bf16x8 v1, v2;
            v1[0]=(short)f2bf(a0.x); v1[1]=(short)f2bf(a0.y); v1[2]=(short)f2bf(a0.z); v1[3]=(short)f2bf(a0.w);
            v1[4]=(short)f2bf(a1.x); v1[5]=(short)f2bf(a1.y); v1[6]=(short)f2bf(a1.z); v1[7]=(short)f2bf(a1.w);
            v2[0]=(short)f2bf(c0.x); v2[1]=(short)f2bf(c0.y); v2[2]=(short)f2bf(c0.z); v2[3]=(short)f2bf(c0.w);
            v2[4]=(short)f2bf(c1.x); v2[5]=(short)f2bf(c1.y); v2[6]=(short)f2bf(c1.z); v2[7]=(short)f2bf(c1.w);
            bWg1[ct][kt] = v1;
            bWg2[ct][kt] = v2;
        }
        // Gamma[dout][q]: exact factorization of pos (incl. bpe) through 34 features
        const float* wrow = Wpe + dout*NPOS_;
        float bias = bpe[dout] + wrow[0]*xm0 + wrow[1]*xm1 + wrow[2]*xm2;
        #pragma unroll
        for (int kt = 0; kt < 2; ++kt) {
            bf16x8 g;
            #pragma unroll
            for (int e = 0; e < 8; ++e) {
                const int qq = kt*32 + lg*8 + e;
                float val;
                if (qq == 0) val = bias;
                else if (qq < 4) val = -wrow[qq-1];
                else if (qq < 34) {
                    const int u = qq - 4, fi = u/6, rem = u - fi*6, j = rem >> 1;
                    const float Ws = wrow[3 + 6*fi + j];
                    const float Wc = wrow[3 + 6*fi + 3 + j];
                    const float fr = fi==0?1.f:(fi==1?8.75f:(fi==2?16.5f:(fi==3?24.25f:32.f)));
                    const float am = fr * (j==0?xm0:(j==1?xm1:xm2));
                    const float sm = __sinf(am), cm = __cosf(am);
                    val = (rem & 1) ? (Wc*sm - Ws*cm) : (Ws*sm + Wc*cm);
                } else val = 0.f;
                g[e] = (short)f2bf(val);
            }
            bG[ct][kt] = g;
        }
        bg1_c[ct] = bg1[dout];
        bg2_c[ct] = bg2[dout];
        q_c[ct]   = qb[row*D_ + dout];
    }

    f32x4 pos[2][2];
    auto posedges = [&]() {   // sF (current tile) @ Gamma^T; edges via kreg -> sX
        #pragma unroll
        for (int rt = 0; rt < 2; ++rt)
        #pragma unroll
        for (int ct = 0; ct < 2; ++ct) {
            f32x4 acc = {0.f, 0.f, 0.f, 0.f};
            #pragma unroll
            for (int kt = 0; kt < 2; ++kt) {
                const int r16 = rb2*32 + rt*16 + lr;
                const int idx = (r16*64 + kt*32 + lg*8) ^ ((r16 & 7) << 3);
                bf16x8 a = *(const bf16x8*)&sF[idx];
                acc = MFMA(a, bG[ct][kt], acc);
            }
            pos[rt][ct] = acc;
        }
        #pragma unroll
        for (int rt = 0; rt < 2; ++rt)
        #pragma unroll
        for (int ct = 0; ct < 2; ++ct) {
            const int d = (ct0 + ct)*16 + lr;
            #pragma unroll
            for (int r = 0; r < 4; ++r) {
                const int rr = rb2*32 + rt*16 + lg*4 + r;
                const float e = pos[rt][ct][r] + q_c[ct] - kreg[rt][ct][r];
                sX[(rr*128 + d) ^ ((rr & 7) << 3)] = f2bf(e);
            }
        }
    };

    // ---- prologue pipeline fill ----
    *(uint4*)&sF[t*8] = fst;
    __syncthreads();
    posedges();            // pos(0), sX(0)
    __syncthreads();

    float res_p[2] = {0.f, 0.f}, s_p[2] = {0.f, 0.f};

    for (int it = 0; it < ITERS_; ++it) {
        const int n0 = it * NT_;
        const bool more = (it < ITERS_ - 1);

        // ---- A: stage F(it+1) + loadK(it+1) + loadV(it); Wg1 GEMM sX->sH ----
        if (more) {
            fst = *(const uint4*)(gF + (size_t)(brow + n0 + NT_)*64 + t*8);
            loadK(n0 + NT_);
        }
        loadV(n0);
        f32x4 hacc[2][2];
        #pragma unroll
        for (int rt = 0; rt < 2; ++rt) {
            hacc[rt][0] = (f32x4){bg1_c[0], bg1_c[0], bg1_c[0], bg1_c[0]};
            hacc[rt][1] = (f32x4){bg1_c[1], bg1_c[1], bg1_c[1], bg1_c[1]};
            #pragma unroll
            for (int kt = 0; kt < 4; ++kt) {
                const int r16 = rb2*32 + rt*16 + lr;
                const int idx = (r16*128 + kt*32 + lg*8) ^ ((r16 & 7) << 3);
                bf16x8 a = *(const bf16x8*)&sX[idx];
                hacc[rt][0] = MFMA(a, bWg1[0][kt], hacc[rt][0]);
                hacc[rt][1] = MFMA(a, bWg1[1][kt], hacc[rt][1]);
            }
        }
        #pragma unroll
        for (int rt = 0; rt < 2; ++rt)
        #pragma unroll
        for (int ct = 0; ct < 2; ++ct) {
            const int d = (ct0 + ct)*16 + lr;
            #pragma unroll
            for (int r = 0; r < 4; ++r) {
                const int rr = rb2*32 + rt*16 + lg*4 + r;
                sH[(rr*128 + d) ^ ((rr & 7) << 3)] = f2bf(fmaxf(hacc[rt][ct][r], 0.f));
            }
        }
        if (more) *(uint4*)&sF[t*8] = fst;   // F(it+1) lands before barrier
        __syncthreads();

        // ---- B: Wg2 GEMM; exp/accum with pos(it),vreg; then pos(it+1)+edges->sX ----
        f32x4 lacc[2][2];
        #pragma unroll
        for (int rt = 0; rt < 2; ++rt) {
            lacc[rt][0] = (f32x4){bg2_c[0], bg2_c[0], bg2_c[0], bg2_c[0]};
            lacc[rt][1] = (f32x4){bg2_c[1], bg2_c[1], bg2_c[1], bg2_c[1]};
            #pragma unroll
            for (int kt = 0; kt < 4; ++kt) {
                const int r16 = rb2*32 + rt*16 + lr;
                const int idx = (r16*128 + kt*32 + lg*8) ^ ((r16 & 7) << 3);
                bf16x8 a = *(const bf16x8*)&sH[idx];
                lacc[rt][0] = MFMA(a, bWg2[0][kt], lacc[rt][0]);
                lacc[rt][1] = MFMA(a, bWg2[1][kt], lacc[rt][1]);
            }
        }
        #pragma unroll
        for (int rt = 0; rt < 2; ++rt)
        #pragma unroll
        for (int ct = 0; ct < 2; ++ct) {
            #pragma unroll
            for (int r = 0; r < 4; ++r) {
                const float wgt = __expf(lacc[rt][ct][r]);
                const float vp  = vreg[rt][ct][r] + pos[rt][ct][r];
                res_p[ct] += wgt * vp;
                s_p[ct]   += wgt;
            }
        }
        if (more) {
            posedges();          // overwrites pos with tile it+1; writes sX(it+1)
            __syncthreads();
        }
    }

    // ---- cross-lane (n) reduce, then cross-rb2 reduce via LDS ----
    #pragma unroll
    for (int ct = 0; ct < 2; ++ct) {
        #pragma unroll
        for (int off = 16; off < 64; off <<= 1) {
            res_p[ct] += __shfl_xor(res_p[ct], off, 64);
            s_p[ct]   += __shfl_xor(s_p[ct], off, 64);
        }
    }
    if (lg == 0) {
        #pragma unroll
        for (int ct = 0; ct < 2; ++ct) {
            const int d = (ct0 + ct)*16 + lr;
            sRed[(rb2*2+0)*128 + d] = res_p[ct];
            sRed[(rb2*2+1)*128 + d] = s_p[ct];
        }
    }
    __syncthreads();
    if (t < D_) {
        const float rsum = sRed[t]       + sRed[2*128 + t];
        const float ssum = sRed[128 + t] + sRed[3*128 + t];
        float fres = graw[row*D_ + t];
        if (use_stats) fres = bn_apply(fres, stats_in, gam_in, bet_in, t);
        const float val = rsum / ssum + fres;
        gout[row*D_ + t] = val;
        atomicAdd(&stats_out[t], val);
        atomicAdd(&stats_out[128 + t], val*val);
    }
}

// ---------------- elementwise MLP: 4 rows/block ----------------
__global__ __launch_bounds__(128) void em_kernel(const float* __restrict__ graw,
    const float* __restrict__ stats_in, const float* __restrict__ gam_in, const float* __restrict__ bet_in,
    const float* __restrict__ W1, const float* __restrict__ b1,
    const float* __restrict__ W2, const float* __restrict__ b2,
    float* __restrict__ gout, float* __restrict__ stats_out)
{
    __shared__ float rows[4][D_], y1[4][D_];
    const int r0 = blockIdx.x*4, d = threadIdx.x;
    float fn[4];
    #pragma unroll
    for (int rr = 0; rr < 4; ++rr) {
        fn[rr] = bn_apply(graw[(r0+rr)*D_ + d], stats_in, gam_in, bet_in, d);
        rows[rr][d] = fn[rr];
    }
    __syncthreads();
    float a[4] = {b1[d], b1[d], b1[d], b1[d]};
    #pragma unroll 4
    for (int e4 = 0; e4 < D_/4; ++e4) {
        float4 w = *(const float4*)(W1 + d*D_ + e4*4);
        #pragma unroll
        for (int rr = 0; rr < 4; ++rr) {
            float4 x = *(const float4*)&rows[rr][e4*4];
            a[rr] += w.x*x.x + w.y*x.y + w.z*x.z + w.w*x.w;
        }
    }
    #pragma unroll
    for (int rr = 0; rr < 4; ++rr) y1[rr][d] = fmaxf(a[rr], 0.f);
    __syncthreads();
    float a2[4] = {b2[d], b2[d], b2[d], b2[d]};
    #pragma unroll 4
    for (int e4 = 0; e4 < D_/4; ++e4) {
        float4 w = *(const float4*)(W2 + d*D_ + e4*4);
        #pragma unroll
        for (int rr = 0; rr < 4; ++rr) {
            float4 x = *(const float4*)&y1[rr][e4*4];
            a2[rr] += w.x*x.x + w.y*x.y + w.z*x.z + w.w*x.w;
        }
    }
    #pragma unroll
    for (int rr = 0; rr < 4; ++rr) {
        const float g2 = fn[rr] + fmaxf(a2[rr], 0.f);
        gout[(r0+rr)*D_ + d] = g2;
        atomicAdd(&stats_out[d], g2);
        atomicAdd(&stats_out[128+d], g2*g2);
    }
}

// ---------------- final head: 4 rows/block ----------------
__global__ __launch_bounds__(256) void final_kernel(const float* __restrict__ graw,
    const float* __restrict__ stats_in, const float* __restrict__ gam_in, const float* __restrict__ bet_in,
    const float* __restrict__ W1, const float* __restrict__ b1,
    const float* __restrict__ W2, const float* __restrict__ b2,
    float* __restrict__ e_ws)
{
    __shared__ float rows[4][D_];
    __shared__ float h1[4][LAT_];
    const int r0 = blockIdx.x*4, t = threadIdx.x;
    for (int i = t; i < 4*D_; i += 256) {
        const int rr = i >> 7, d = i & 127;
        rows[rr][d] = bn_apply(graw[(r0+rr)*D_ + d], stats_in, gam_in, bet_in, d);
    }
    __syncthreads();
    float a[4] = {b1[t], b1[t], b1[t], b1[t]};
    #pragma unroll 4
    for (int e4 = 0; e4 < D_/4; ++e4) {
        float4 w = *(const float4*)(W1 + t*D_ + e4*4);
        #pragma unroll
        for (int rr = 0; rr < 4; ++rr) {
            float4 x = *(const float4*)&rows[rr][e4*4];
            a[rr] += w.x*x.x + w.y*x.y + w.z*x.z + w.w*x.w;
        }
    }
    #pragma unroll
    for (int rr = 0; rr < 4; ++rr) h1[rr][t] = fmaxf(a[rr], 0.f);
    __syncthreads();
    float a2[4] = {b2[t], b2[t], b2[t], b2[t]};
    #pragma unroll 4
    for (int e4 = 0; e4 < LAT_/4; ++e4) {
        float4 w = *(const float4*)(W2 + t*LAT_ + e4*4);
        #pragma unroll
        for (int rr = 0; rr < 4; ++rr) {
            float4 x = *(const float4*)&h1[rr][e4*4];
            a2[rr] += w.x*x.x + w.y*x.y + w.z*x.z + w.w*x.w;
        }
    }
    #pragma unroll
    for (int rr = 0; rr < 4; ++rr) e_ws[(r0+rr)*LAT_ + t] = a2[rr];
}

// ---------------- max over points ----------------
__global__ __launch_bounds__(256) void maxred_kernel(const float* __restrict__ e_ws,
                                                     float* __restrict__ out)
{
    int b = blockIdx.x, l = threadIdx.x;
    float m = -INFINITY;
    #pragma unroll 8
    for (int n=0;n<N_;n++) m = fmaxf(m, e_ws[(b*N_+n)*LAT_+l]);
    out[b*LAT_+l] = m;
}

extern "C" void kernel_launch(void* const* d_in, const int* in_sizes, int n_in,
                              void* d_out, int out_size, void* d_ws, size_t ws_size,
                              hipStream_t stream) {
    (void)in_sizes; (void)n_in; (void)out_size; (void)ws_size;
    const float* xyz    = (const float*)d_in[0];
    const float* feats  = (const float*)d_in[1];
    const float* enc_W  = (const float*)d_in[2];
    const float* enc_b  = (const float*)d_in[3];
    const float* tb_Wq  = (const float*)d_in[4];
    const float* tb_Wk  = (const float*)d_in[5];
    const float* tb_Wv  = (const float*)d_in[6];
    const float* tb_Wg1 = (const float*)d_in[7];
    const float* tb_bg1 = (const float*)d_in[8];
    const float* tb_Wg2 = (const float*)d_in[9];
    const float* tb_bg2 = (const float*)d_in[10];
    const float* tb_Wpe = (const float*)d_in[11];
    const float* tb_bpe = (const float*)d_in[12];
    const float* tb_gamma = (const float*)d_in[13];
    const float* tb_beta  = (const float*)d_in[14];
    const float* em_W1  = (const float*)d_in[15];
    const float* em_b1  = (const float*)d_in[16];
    const float* em_W2  = (const float*)d_in[17];
    const float* em_b2  = (const float*)d_in[18];
    const float* em_gamma = (const float*)d_in[19];
    const float* em_beta  = (const float*)d_in[20];
    const float* fcf_W1 = (const float*)d_in[21];
    const float* fcf_b1 = (const float*)d_in[22];
    const float* fcf_W2 = (const float*)d_in[23];
    const float* fcf_b2 = (const float*)d_in[24];
    float* out = (float*)d_out;

    // workspace layout
    float* ws   = (float*)d_ws;
    float* buf0 = ws;                      // ROWS_*D_
    float* buf1 = buf0 + ROWS_*D_;         // ROWS_*D_
    float* qbuf = buf1 + ROWS_*D_;         // ROWS_*D_
    float* ebuf = qbuf + ROWS_*D_;         // ROWS_*LAT_
    float* stats = ebuf + ROWS_*LAT_;      // 5 x 256 floats
    float* sA0 = stats;
    float* sA1 = stats + 256;
    float* sE1 = stats + 512;
    float* sA2 = stats + 768;
    float* sE2 = stats + 1024;
    unsigned short* kbuf = (unsigned short*)(stats + 5*256);       // ROWS_*D_ bf16
    unsigned short* vbuf = kbuf + ROWS_*D_;                        // ROWS_*D_ bf16
    unsigned short* gF   = vbuf + ROWS_*D_;                        // ROWS_*64 bf16

    hipMemsetAsync(stats, 0, 5*256*sizeof(float), stream);

    fprep_kernel<<<(ROWS_*64+255)/256, 256, 0, stream>>>(xyz, gF);
    enc_kernel<<<(ROWS_*D_+255)/256, 256, 0, stream>>>(feats, enc_W, enc_b, buf0);

    const float* gz = tb_gamma;  // dummies for unused-stats calls
    // Layer 0
    qkv_kernel<<<ROWS_/4, 128, 0, stream>>>(buf0, gz, gz, gz, 0,
                                            tb_Wq, tb_Wk, tb_Wv, qbuf, kbuf, vbuf);
    attn_mfma_kernel<<<ROWS_, 512, 0, stream>>>(xyz, buf0, gz, gz, gz, 0,
        qbuf, kbuf, vbuf, gF,
        tb_Wpe, tb_bpe, tb_Wg1, tb_bg1, tb_Wg2, tb_bg2, buf1, sA0);
    // Layer 1
    qkv_kernel<<<ROWS_/4, 128, 0, stream>>>(buf1, sA0, tb_gamma, tb_beta, 1,
                                            tb_Wq + 1*D_*D_, tb_Wk + 1*D_*D_, tb_Wv + 1*D_*D_,
                                            qbuf, kbuf, vbuf);
    attn_mfma_kernel<<<ROWS_, 512, 0, stream>>>(xyz, buf1, sA0, tb_gamma, tb_beta, 1,
        qbuf, kbuf, vbuf, gF,
        tb_Wpe + 1*D_*NPOS_, tb_bpe + 1*D_, tb_Wg1 + 1*D_*D_, tb_bg1 + 1*D_,
        tb_Wg2 + 1*D_*D_, tb_bg2 + 1*D_, buf0, sA1);
    em_kernel<<<ROWS_/4, 128, 0, stream>>>(buf0, sA1, tb_gamma + 1*D_, tb_beta + 1*D_,
                                           em_W1, em_b1, em_W2, em_b2, buf1, sE1);
    // Layer 2
    qkv_kernel<<<ROWS_/4, 128, 0, stream>>>(buf1, sE1, em_gamma, em_beta, 1,
                                            tb_Wq + 2*D_*D_, tb_Wk + 2*D_*D_, tb_Wv + 2*D_*D_,
                                            qbuf, kbuf, vbuf);
    attn_mfma_kernel<<<ROWS_, 512, 0, stream>>>(xyz, buf1, sE1, em_gamma, em_beta, 1,
        qbuf, kbuf, vbuf, gF,
        tb_Wpe + 2*D_*NPOS_, tb_bpe + 2*D_, tb_Wg1 + 2*D_*D_, tb_bg1 + 2*D_,
        tb_Wg2 + 2*D_*D_, tb_bg2 + 2*D_, buf0, sA2);
    em_kernel<<<ROWS_/4, 128, 0, stream>>>(buf0, sA2, tb_gamma + 2*D_, tb_beta + 2*D_,
                                           em_W1 + 1*D_*D_, em_b1 + 1*D_,
                                           em_W2 + 1*D_*D_, em_b2 + 1*D_, buf1, sE2);
    // Head
    final_kernel<<<ROWS_/4, 256, 0, stream>>>(buf1, sE2, em_gamma + 1*D_, em_beta + 1*D_,
                                              fcf_W1, fcf_b1, fcf_W2, fcf_b2, ebuf);
    maxred_kernel<<<B_, 256, 0, stream>>>(ebuf, out);
}

// Round 10
// 556.850 us; speedup vs baseline: 1.2379x; 1.2379x over previous
//
#include <hip/hip_runtime.h>
#include <hip/hip_bf16.h>

#define B_ 2
#define N_ 384
#define D_ 128
#define LAT_ 256
#define NPOS_ 33
#define ROWS_ (B_*N_)   // 768
#define NT_ 64          // n-rows per attn iteration
#define ITERS_ (N_/NT_) // 6

typedef __attribute__((ext_vector_type(8))) short bf16x8;
typedef __attribute__((ext_vector_type(4))) float f32x4;

#define MFMA(a,b,c) __builtin_amdgcn_mfma_f32_16x16x32_bf16((a),(b),(c),0,0,0)

__device__ __forceinline__ unsigned short f2bf(float x) {
    unsigned int u = __float_as_uint(x);
    u += 0x7FFFu + ((u >> 16) & 1u);   // round-to-nearest-even
    return (unsigned short)(u >> 16);
}
__device__ __forceinline__ float bf2f(unsigned short u) {
    return __uint_as_float(((unsigned int)u) << 16);
}

__device__ __forceinline__ float bn_apply(float x, const float* stats, const float* gam,
                                          const float* bet, int d) {
    float s  = stats[d], sq = stats[128 + d];
    float mean = s * (1.f/ROWS_);
    float var  = sq * (1.f/ROWS_) - mean*mean;
    return (x - mean) * rsqrtf(var + 1e-5f) * gam[d] + bet[d];
}

// ---------------- F-feature precompute: gF[n][64] bf16, swizzled, zero-padded ----------------
__global__ __launch_bounds__(256) void fprep_kernel(const float* __restrict__ xyz,
                                                    unsigned short* __restrict__ gF) {
    int i = blockIdx.x*256 + threadIdx.x;      // over ROWS_*64
    if (i >= ROWS_*64) return;
    int n = i >> 6, q = i & 63;
    float val;
    if (q == 0) val = 1.f;
    else if (q < 4) val = 4.f*xyz[n*3 + (q-1)];
    else if (q < 34) {
        int u = q-4, fi = u/6, rem = u - fi*6, j = rem >> 1;
        const float fr = fi==0?1.f:(fi==1?8.75f:(fi==2?16.5f:(fi==3?24.25f:32.f)));
        float a = fr*4.f*xyz[n*3+j];
        val = (rem & 1) ? __sinf(a) : __cosf(a);
    } else val = 0.f;
    gF[n*64 + (q ^ ((n & 7) << 3))] = f2bf(val);
}

// ---------------- Psi precompute: psi[layer][e][34], cols 0..32 = Wg1@Wpe, col 33 = Wg1@bpe ----
__global__ __launch_bounds__(128) void psi_kernel(
    const float* __restrict__ Wg1, const float* __restrict__ Wpe,
    const float* __restrict__ bpe, float* __restrict__ psi)
{
    const int blk = blockIdx.x, layer = blk / 34, p = blk - layer*34;
    const float* wg1 = Wg1 + layer*D_*D_;
    __shared__ float col[D_];
    const int e = threadIdx.x;
    col[e] = (p < NPOS_) ? Wpe[layer*D_*NPOS_ + e*NPOS_ + p] : bpe[layer*D_ + e];
    __syncthreads();
    float acc = 0.f;
    #pragma unroll 4
    for (int d4 = 0; d4 < 32; ++d4) {
        float4 w = *(const float4*)(wg1 + e*D_ + d4*4);
        acc += w.x*col[d4*4] + w.y*col[d4*4+1] + w.z*col[d4*4+2] + w.w*col[d4*4+3];
    }
    psi[layer*D_*34 + e*34 + p] = acc;
}

// ---------------- encode ----------------
__global__ __launch_bounds__(256) void enc_kernel(const float* __restrict__ feats,
                           const float* __restrict__ W,
                           const float* __restrict__ bias,
                           float* __restrict__ f) {
    int i = blockIdx.x*256 + threadIdx.x;
    if (i >= ROWS_*D_) return;
    int r = i >> 7, d = i & 127;
    f[i] = feats[r]*W[d] + bias[d];
}

// ---------------- qkvkw: q,k,v + fold Wg1: hb = q@Wg1^T+bg1 (f32), kw = k@Wg1^T (bf16) ----------------
__global__ __launch_bounds__(128) void qkvkw_kernel(const float* __restrict__ graw,
    const float* __restrict__ stats, const float* __restrict__ gam, const float* __restrict__ bet,
    int use_stats,
    const float* __restrict__ Wq, const float* __restrict__ Wk, const float* __restrict__ Wv,
    const float* __restrict__ Wg1, const float* __restrict__ bg1,
    float* __restrict__ hb, unsigned short* __restrict__ kw16, unsigned short* __restrict__ v16)
{
    __shared__ float rows[4][D_], qrows[4][D_], krows[4][D_];
    const int r0 = blockIdx.x*4, d = threadIdx.x;
    #pragma unroll
    for (int rr = 0; rr < 4; ++rr) {
        float x = graw[(r0+rr)*D_ + d];
        if (use_stats) x = bn_apply(x, stats, gam, bet, d);
        rows[rr][d] = x;
    }
    __syncthreads();
    float aq[4] = {0,0,0,0}, ak[4] = {0,0,0,0}, av[4] = {0,0,0,0};
    #pragma unroll 4
    for (int e4 = 0; e4 < D_/4; ++e4) {
        float4 wq = *(const float4*)(Wq + d*D_ + e4*4);
        float4 wk = *(const float4*)(Wk + d*D_ + e4*4);
        float4 wv = *(const float4*)(Wv + d*D_ + e4*4);
        #pragma unroll
        for (int rr = 0; rr < 4; ++rr) {
            float4 x = *(const float4*)&rows[rr][e4*4];
            aq[rr] += wq.x*x.x + wq.y*x.y + wq.z*x.z + wq.w*x.w;
            ak[rr] += wk.x*x.x + wk.y*x.y + wk.z*x.z + wk.w*x.w;
            av[rr] += wv.x*x.x + wv.y*x.y + wv.z*x.z + wv.w*x.w;
        }
    }
    #pragma unroll
    for (int rr = 0; rr < 4; ++rr) {
        v16[(r0+rr)*D_ + d] = f2bf(av[rr]);
        qrows[rr][d] = aq[rr];
        krows[rr][d] = ak[rr];
    }
    __syncthreads();
    float hq[4], hk[4] = {0,0,0,0};
    #pragma unroll
    for (int rr = 0; rr < 4; ++rr) hq[rr] = bg1[d];
    #pragma unroll 4
    for (int e4 = 0; e4 < D_/4; ++e4) {
        float4 w = *(const float4*)(Wg1 + d*D_ + e4*4);
        #pragma unroll
        for (int rr = 0; rr < 4; ++rr) {
            float4 xq = *(const float4*)&qrows[rr][e4*4];
            float4 xk = *(const float4*)&krows[rr][e4*4];
            hq[rr] += w.x*xq.x + w.y*xq.y + w.z*xq.z + w.w*xq.w;
            hk[rr] += w.x*xk.x + w.y*xk.y + w.z*xk.z + w.w*xk.w;
        }
    }
    #pragma unroll
    for (int rr = 0; rr < 4; ++rr) {
        hb[(r0+rr)*D_ + d]   = hq[rr];
        kw16[(r0+rr)*D_ + d] = f2bf(hk[rr]);
    }
}

// ---------------- MFMA attention: Theta-folded, no edges tensor, 2 barriers/iter ----------------
// 512 thr = 8 waves: rb2 = w>>2 (32-row n-half), ct0 = (w&3)*2 (two 16-d tiles).
// A(it): [load V(it), F(it+1)] hacc=F@Theta (8 MFMA), pos=F@Gamma (8 MFMA);
//        h = relu(hacc + hb - KW); 16x ds_write_b16 -> sH | bar
// B(it): [store F(it+1)->sF, load KW(it+1)] lacc=sH@Wg2 (16 MFMA) + bg2;
//        w=exp(lacc); res += w*(V+pos); s += w | bar
__global__ __launch_bounds__(512) void attn_mfma_kernel(
    const float* __restrict__ xyz, const float* __restrict__ graw,
    const float* __restrict__ stats_in, const float* __restrict__ gam_in,
    const float* __restrict__ bet_in, int use_stats,
    const float* __restrict__ hbb,
    const unsigned short* __restrict__ kwb, const unsigned short* __restrict__ vb,
    const unsigned short* __restrict__ gF,
    const float* __restrict__ psiL,
    const float* __restrict__ Wpe, const float* __restrict__ bpe,
    const float* __restrict__ Wg2, const float* __restrict__ bg2,
    float* __restrict__ gout, float* __restrict__ stats_out)
{
    __shared__ unsigned short sF[NT_*64];    // F features bf16, swizzled (8KB)
    __shared__ unsigned short sH[NT_*128];   // h bf16, swizzled (16KB)
    __shared__ float sRed[4*128];

    const int t   = threadIdx.x;
    const int w   = t >> 6;
    const int l   = t & 63;
    const int lr  = l & 15;
    const int lg  = l >> 4;
    const int rb2 = w >> 2;
    const int ct0 = (w & 3) * 2;

    const int row  = blockIdx.x;
    const int b    = row / N_;
    const int brow = b * N_;

    // ---- early issue: F(0) + KW(0) ----
    uint4 freg = *(const uint4*)(gF + (size_t)brow*64 + t*8);
    unsigned short kw_us[2][2][4];
    unsigned short v_us[2][2][4];
    auto loadKW = [&](int n0) {
        #pragma unroll
        for (int rt = 0; rt < 2; ++rt)
        #pragma unroll
        for (int ct = 0; ct < 2; ++ct) {
            const int d = (ct0 + ct)*16 + lr;
            #pragma unroll
            for (int r = 0; r < 4; ++r) {
                const int rr = rb2*32 + rt*16 + lg*4 + r;
                kw_us[rt][ct][r] = kwb[(brow + n0 + rr)*D_ + d];
            }
        }
    };
    auto loadV = [&](int n0) {
        #pragma unroll
        for (int rt = 0; rt < 2; ++rt)
        #pragma unroll
        for (int ct = 0; ct < 2; ++ct) {
            const int d = (ct0 + ct)*16 + lr;
            #pragma unroll
            for (int r = 0; r < 4; ++r) {
                const int rr = rb2*32 + rt*16 + lg*4 + r;
                v_us[rt][ct][r] = vb[(brow + n0 + rr)*D_ + d];
            }
        }
    };
    loadKW(0);

    // ---- prologue: frags. bG from Wpe (pos for accum); bT from psi (pos@Wg1 fold) ----
    bf16x8 bWg2[2][4], bG[2][2], bT[2][2];
    float  hb_c[2], bg2_c[2];

    const float xm0 = 4.f*xyz[row*3+0];
    const float xm1 = 4.f*xyz[row*3+1];
    const float xm2 = 4.f*xyz[row*3+2];

    #pragma unroll
    for (int ct = 0; ct < 2; ++ct) {
        const int dout = (ct0 + ct) * 16 + lr;
        #pragma unroll
        for (int kt = 0; kt < 4; ++kt) {
            const float* p2 = Wg2 + dout * D_ + kt * 32 + lg * 8;
            float4 c0 = *(const float4*)(p2);
            float4 c1 = *(const float4*)(p2 + 4);
            bf16x8 v2;
            v2[0]=(short)f2bf(c0.x); v2[1]=(short)f2bf(c0.y); v2[2]=(short)f2bf(c0.z); v2[3]=(short)f2bf(c0.w);
            v2[4]=(short)f2bf(c1.x); v2[5]=(short)f2bf(c1.y); v2[6]=(short)f2bf(c1.z); v2[7]=(short)f2bf(c1.w);
            bWg2[ct][kt] = v2;
        }
        // Gamma[dout][q] from Wpe/bpe (verified r8 construction)
        {
            const float* wrow = Wpe + dout*NPOS_;
            float bias = bpe[dout] + wrow[0]*xm0 + wrow[1]*xm1 + wrow[2]*xm2;
            #pragma unroll
            for (int kt = 0; kt < 2; ++kt) {
                bf16x8 g;
                #pragma unroll
                for (int e = 0; e < 8; ++e) {
                    const int qq = kt*32 + lg*8 + e;
                    float val;
                    if (qq == 0) val = bias;
                    else if (qq < 4) val = -wrow[qq-1];
                    else if (qq < 34) {
                        const int u = qq - 4, fi = u/6, rem = u - fi*6, j = rem >> 1;
                        const float Ws = wrow[3 + 6*fi + j];
                        const float Wc = wrow[3 + 6*fi + 3 + j];
                        const float fr = fi==0?1.f:(fi==1?8.75f:(fi==2?16.5f:(fi==3?24.25f:32.f)));
                        const float am = fr * (j==0?xm0:(j==1?xm1:xm2));
                        const float sm = __sinf(am), cm = __cosf(am);
                        val = (rem & 1) ? (Wc*sm - Ws*cm) : (Ws*sm + Wc*cm);
                    } else val = 0.f;
                    g[e] = (short)f2bf(val);
                }
                bG[ct][kt] = g;
            }
        }
        // Theta[dout][q] from psi row (same construction, psi replaces Wpe; col33 = Wg1@bpe)
        {
            const float* prow = psiL + dout*34;
            float bias = prow[33] + prow[0]*xm0 + prow[1]*xm1 + prow[2]*xm2;
            #pragma unroll
            for (int kt = 0; kt < 2; ++kt) {
                bf16x8 g;
                #pragma unroll
                for (int e = 0; e < 8; ++e) {
                    const int qq = kt*32 + lg*8 + e;
                    float val;
                    if (qq == 0) val = bias;
                    else if (qq < 4) val = -prow[qq-1];
                    else if (qq < 34) {
                        const int u = qq - 4, fi = u/6, rem = u - fi*6, j = rem >> 1;
                        const float Ws = prow[3 + 6*fi + j];
                        const float Wc = prow[3 + 6*fi + 3 + j];
                        const float fr = fi==0?1.f:(fi==1?8.75f:(fi==2?16.5f:(fi==3?24.25f:32.f)));
                        const float am = fr * (j==0?xm0:(j==1?xm1:xm2));
                        const float sm = __sinf(am), cm = __cosf(am);
                        val = (rem & 1) ? (Wc*sm - Ws*cm) : (Ws*sm + Wc*cm);
                    } else val = 0.f;
                    g[e] = (short)f2bf(val);
                }
                bT[ct][kt] = g;
            }
        }
        hb_c[ct]  = hbb[row*D_ + dout];
        bg2_c[ct] = bg2[dout];
    }

    // ---- stage F(0) ----
    *(uint4*)&sF[t*8] = freg;
    __syncthreads();

    float res_p[2] = {0.f, 0.f}, s_p[2] = {0.f, 0.f};
    f32x4 pos[2][2];

    for (int it = 0; it < ITERS_; ++it) {
        const int n0 = it * NT_;
        const bool more = (it < ITERS_ - 1);

        // ---- A: prefetch V(it), F(it+1); hacc=F@T, pos=F@G; h -> sH ----
        loadV(n0);
        if (more) freg = *(const uint4*)(gF + (size_t)(brow + n0 + NT_)*64 + t*8);
        f32x4 hacc[2][2];
        #pragma unroll
        for (int rt = 0; rt < 2; ++rt) {
            const int r16 = rb2*32 + rt*16 + lr;
            const int sw  = (r16 & 7) << 3;
            bf16x8 a0 = *(const bf16x8*)&sF[(r16*64 +  0 + lg*8) ^ sw];
            bf16x8 a1 = *(const bf16x8*)&sF[(r16*64 + 32 + lg*8) ^ sw];
            #pragma unroll
            for (int ct = 0; ct < 2; ++ct) {
                f32x4 z = {0.f,0.f,0.f,0.f};
                hacc[rt][ct] = MFMA(a1, bT[ct][1], MFMA(a0, bT[ct][0], z));
                pos[rt][ct]  = MFMA(a1, bG[ct][1], MFMA(a0, bG[ct][0], z));
            }
        }
        #pragma unroll
        for (int rt = 0; rt < 2; ++rt)
        #pragma unroll
        for (int ct = 0; ct < 2; ++ct) {
            const int d = (ct0 + ct)*16 + lr;
            #pragma unroll
            for (int r = 0; r < 4; ++r) {
                const int rr = rb2*32 + rt*16 + lg*4 + r;
                const float hv = hacc[rt][ct][r] + hb_c[ct] - bf2f(kw_us[rt][ct][r]);
                sH[(rr*128 + d) ^ ((rr & 7) << 3)] = f2bf(fmaxf(hv, 0.f));
            }
        }
        __syncthreads();

        // ---- B: stage F(it+1); prefetch KW(it+1); Wg2 GEMM; exp/accum ----
        if (more) {
            *(uint4*)&sF[t*8] = freg;
            loadKW(n0 + NT_);
        }
        f32x4 lacc[2][2];
        #pragma unroll
        for (int rt = 0; rt < 2; ++rt) {
            lacc[rt][0] = (f32x4){bg2_c[0], bg2_c[0], bg2_c[0], bg2_c[0]};
            lacc[rt][1] = (f32x4){bg2_c[1], bg2_c[1], bg2_c[1], bg2_c[1]};
            #pragma unroll
            for (int kt = 0; kt < 4; ++kt) {
                const int r16 = rb2*32 + rt*16 + lr;
                const int idx = (r16*128 + kt*32 + lg*8) ^ ((r16 & 7) << 3);
                bf16x8 a = *(const bf16x8*)&sH[idx];
                lacc[rt][0] = MFMA(a, bWg2[0][kt], lacc[rt][0]);
                lacc[rt][1] = MFMA(a, bWg2[1][kt], lacc[rt][1]);
            }
        }
        #pragma unroll
        for (int rt = 0; rt < 2; ++rt)
        #pragma unroll
        for (int ct = 0; ct < 2; ++ct) {
            #pragma unroll
            for (int r = 0; r < 4; ++r) {
                const float wgt = __expf(lacc[rt][ct][r]);
                const float vp  = bf2f(v_us[rt][ct][r]) + pos[rt][ct][r];
                res_p[ct] += wgt * vp;
                s_p[ct]   += wgt;
            }
        }
        __syncthreads();
    }

    // ---- cross-lane (n) reduce, then cross-rb2 reduce via LDS ----
    #pragma unroll
    for (int ct = 0; ct < 2; ++ct) {
        #pragma unroll
        for (int off = 16; off < 64; off <<= 1) {
            res_p[ct] += __shfl_xor(res_p[ct], off, 64);
            s_p[ct]   += __shfl_xor(s_p[ct], off, 64);
        }
    }
    if (lg == 0) {
        #pragma unroll
        for (int ct = 0; ct < 2; ++ct) {
            const int d = (ct0 + ct)*16 + lr;
            sRed[(rb2*2+0)*128 + d] = res_p[ct];
            sRed[(rb2*2+1)*128 + d] = s_p[ct];
        }
    }
    __syncthreads();
    if (t < D_) {
        const float rsum = sRed[t]       + sRed[2*128 + t];
        const float ssum = sRed[128 + t] + sRed[3*128 + t];
        float fres = graw[row*D_ + t];
        if (use_stats) fres = bn_apply(fres, stats_in, gam_in, bet_in, t);
        const float val = rsum / ssum + fres;
        gout[row*D_ + t] = val;
        atomicAdd(&stats_out[t], val);
        atomicAdd(&stats_out[128 + t], val*val);
    }
}

// ---------------- elementwise MLP: 4 rows/block ----------------
__global__ __launch_bounds__(128) void em_kernel(const float* __restrict__ graw,
    const float* __restrict__ stats_in, const float* __restrict__ gam_in, const float* __restrict__ bet_in,
    const float* __restrict__ W1, const float* __restrict__ b1,
    const float* __restrict__ W2, const float* __restrict__ b2,
    float* __restrict__ gout, float* __restrict__ stats_out)
{
    __shared__ float rows[4][D_], y1[4][D_];
    const int r0 = blockIdx.x*4, d = threadIdx.x;
    float fn[4];
    #pragma unroll
    for (int rr = 0; rr < 4; ++rr) {
        fn[rr] = bn_apply(graw[(r0+rr)*D_ + d], stats_in, gam_in, bet_in, d);
        rows[rr][d] = fn[rr];
    }
    __syncthreads();
    float a[4] = {b1[d], b1[d], b1[d], b1[d]};
    #pragma unroll 4
    for (int e4 = 0; e4 < D_/4; ++e4) {
        float4 w = *(const float4*)(W1 + d*D_ + e4*4);
        #pragma unroll
        for (int rr = 0; rr < 4; ++rr) {
            float4 x = *(const float4*)&rows[rr][e4*4];
            a[rr] += w.x*x.x + w.y*x.y + w.z*x.z + w.w*x.w;
        }
    }
    #pragma unroll
    for (int rr = 0; rr < 4; ++rr) y1[rr][d] = fmaxf(a[rr], 0.f);
    __syncthreads();
    float a2[4] = {b2[d], b2[d], b2[d], b2[d]};
    #pragma unroll 4
    for (int e4 = 0; e4 < D_/4; ++e4) {
        float4 w = *(const float4*)(W2 + d*D_ + e4*4);
        #pragma unroll
        for (int rr = 0; rr < 4; ++rr) {
            float4 x = *(const float4*)&y1[rr][e4*4];
            a2[rr] += w.x*x.x + w.y*x.y + w.z*x.z + w.w*x.w;
        }
    }
    #pragma unroll
    for (int rr = 0; rr < 4; ++rr) {
        const float g2 = fn[rr] + fmaxf(a2[rr], 0.f);
        gout[(r0+rr)*D_ + d] = g2;
        atomicAdd(&stats_out[d], g2);
        atomicAdd(&stats_out[128+d], g2*g2);
    }
}

// ---------------- final head: 4 rows/block ----------------
__global__ __launch_bounds__(256) void final_kernel(const float* __restrict__ graw,
    const float* __restrict__ stats_in, const float* __restrict__ gam_in, const float* __restrict__ bet_in,
    const float* __restrict__ W1, const float* __restrict__ b1,
    const float* __restrict__ W2, const float* __restrict__ b2,
    float* __restrict__ e_ws)
{
    __shared__ float rows[4][D_];
    __shared__ float h1[4][LAT_];
    const int r0 = blockIdx.x*4, t = threadIdx.x;
    for (int i = t; i < 4*D_; i += 256) {
        const int rr = i >> 7, d = i & 127;
        rows[rr][d] = bn_apply(graw[(r0+rr)*D_ + d], stats_in, gam_in, bet_in, d);
    }
    __syncthreads();
    float a[4] = {b1[t], b1[t], b1[t], b1[t]};
    #pragma unroll 4
    for (int e4 = 0; e4 < D_/4; ++e4) {
        float4 w = *(const float4*)(W1 + t*D_ + e4*4);
        #pragma unroll
        for (int rr = 0; rr < 4; ++rr) {
            float4 x = *(const float4*)&rows[rr][e4*4];
            a[rr] += w.x*x.x + w.y*x.y + w.z*x.z + w.w*x.w;
        }
    }
    #pragma unroll
    for (int rr = 0; rr < 4; ++rr) h1[rr][t] = fmaxf(a[rr], 0.f);
    __syncthreads();
    float a2[4] = {b2[t], b2[t], b2[t], b2[t]};
    #pragma unroll 4
    for (int e4 = 0; e4 < LAT_/4; ++e4) {
        float4 w = *(const float4*)(W2 + t*LAT_ + e4*4);
        #pragma unroll
        for (int rr = 0; rr < 4; ++rr) {
            float4 x = *(const float4*)&h1[rr][e4*4];
            a2[rr] += w.x*x.x + w.y*x.y + w.z*x.z + w.w*x.w;
        }
    }
    #pragma unroll
    for (int rr = 0; rr < 4; ++rr) e_ws[(r0+rr)*LAT_ + t] = a2[rr];
}

// ---------------- max over points ----------------
__global__ __launch_bounds__(256) void maxred_kernel(const float* __restrict__ e_ws,
                                                     float* __restrict__ out)
{
    int b = blockIdx.x, l = threadIdx.x;
    float m = -INFINITY;
    #pragma unroll 8
    for (int n=0;n<N_;n++) m = fmaxf(m, e_ws[(b*N_+n)*LAT_+l]);
    out[b*LAT_+l] = m;
}

extern "C" void kernel_launch(void* const* d_in, const int* in_sizes, int n_in,
                              void* d_out, int out_size, void* d_ws, size_t ws_size,
                              hipStream_t stream) {
    (void)in_sizes; (void)n_in; (void)out_size; (void)ws_size;
    const float* xyz    = (const float*)d_in[0];
    const float* feats  = (const float*)d_in[1];
    const float* enc_W  = (const float*)d_in[2];
    const float* enc_b  = (const float*)d_in[3];
    const float* tb_Wq  = (const float*)d_in[4];
    const float* tb_Wk  = (const float*)d_in[5];
    const float* tb_Wv  = (const float*)d_in[6];
    const float* tb_Wg1 = (const float*)d_in[7];
    const float* tb_bg1 = (const float*)d_in[8];
    const float* tb_Wg2 = (const float*)d_in[9];
    const float* tb_bg2 = (const float*)d_in[10];
    const float* tb_Wpe = (const float*)d_in[11];
    const float* tb_bpe = (const float*)d_in[12];
    const float* tb_gamma = (const float*)d_in[13];
    const float* tb_beta  = (const float*)d_in[14];
    const float* em_W1  = (const float*)d_in[15];
    const float* em_b1  = (const float*)d_in[16];
    const float* em_W2  = (const float*)d_in[17];
    const float* em_b2  = (const float*)d_in[18];
    const float* em_gamma = (const float*)d_in[19];
    const float* em_beta  = (const float*)d_in[20];
    const float* fcf_W1 = (const float*)d_in[21];
    const float* fcf_b1 = (const float*)d_in[22];
    const float* fcf_W2 = (const float*)d_in[23];
    const float* fcf_b2 = (const float*)d_in[24];
    float* out = (float*)d_out;

    // workspace layout
    float* ws   = (float*)d_ws;
    float* buf0 = ws;                      // ROWS_*D_  f32
    float* buf1 = buf0 + ROWS_*D_;         // ROWS_*D_  f32
    float* hbb  = buf1 + ROWS_*D_;         // ROWS_*D_  f32 (q@Wg1+bg1)
    float* ebuf = hbb  + ROWS_*D_;         // ROWS_*LAT_ f32
    float* psi  = ebuf + ROWS_*LAT_;       // 3*128*34 f32
    float* stats = psi + 3*D_*34;          // 5 x 256 f32
    float* sA0 = stats;
    float* sA1 = stats + 256;
    float* sE1 = stats + 512;
    float* sA2 = stats + 768;
    float* sE2 = stats + 1024;
    unsigned short* kwbuf = (unsigned short*)(stats + 5*256);      // ROWS_*D_ bf16
    unsigned short* vbuf  = kwbuf + ROWS_*D_;                      // ROWS_*D_ bf16
    unsigned short* gF    = vbuf + ROWS_*D_;                       // ROWS_*64 bf16

    hipMemsetAsync(stats, 0, 5*256*sizeof(float), stream);

    fprep_kernel<<<(ROWS_*64+255)/256, 256, 0, stream>>>(xyz, gF);
    psi_kernel<<<3*34, 128, 0, stream>>>(tb_Wg1, tb_Wpe, tb_bpe, psi);
    enc_kernel<<<(ROWS_*D_+255)/256, 256, 0, stream>>>(feats, enc_W, enc_b, buf0);

    const float* gz = tb_gamma;  // dummies for unused-stats calls
    // Layer 0
    qkvkw_kernel<<<ROWS_/4, 128, 0, stream>>>(buf0, gz, gz, gz, 0,
        tb_Wq, tb_Wk, tb_Wv, tb_Wg1, tb_bg1, hbb, kwbuf, vbuf);
    attn_mfma_kernel<<<ROWS_, 512, 0, stream>>>(xyz, buf0, gz, gz, gz, 0,
        hbb, kwbuf, vbuf, gF, psi,
        tb_Wpe, tb_bpe, tb_Wg2, tb_bg2, buf1, sA0);
    // Layer 1
    qkvkw_kernel<<<ROWS_/4, 128, 0, stream>>>(buf1, sA0, tb_gamma, tb_beta, 1,
        tb_Wq + 1*D_*D_, tb_Wk + 1*D_*D_, tb_Wv + 1*D_*D_,
        tb_Wg1 + 1*D_*D_, tb_bg1 + 1*D_, hbb, kwbuf, vbuf);
    attn_mfma_kernel<<<ROWS_, 512, 0, stream>>>(xyz, buf1, sA0, tb_gamma, tb_beta, 1,
        hbb, kwbuf, vbuf, gF, psi + 1*D_*34,
        tb_Wpe + 1*D_*NPOS_, tb_bpe + 1*D_, tb_Wg2 + 1*D_*D_, tb_bg2 + 1*D_, buf0, sA1);
    em_kernel<<<ROWS_/4, 128, 0, stream>>>(buf0, sA1, tb_gamma + 1*D_, tb_beta + 1*D_,
                                           em_W1, em_b1, em_W2, em_b2, buf1, sE1);
    // Layer 2
    qkvkw_kernel<<<ROWS_/4, 128, 0, stream>>>(buf1, sE1, em_gamma, em_beta, 1,
        tb_Wq + 2*D_*D_, tb_Wk + 2*D_*D_, tb_Wv + 2*D_*D_,
        tb_Wg1 + 2*D_*D_, tb_bg1 + 2*D_, hbb, kwbuf, vbuf);
    attn_mfma_kernel<<<ROWS_, 512, 0, stream>>>(xyz, buf1, sE1, em_gamma, em_beta, 1,
        hbb, kwbuf, vbuf, gF, psi + 2*D_*34,
        tb_Wpe + 2*D_*NPOS_, tb_bpe + 2*D_, tb_Wg2 + 2*D_*D_, tb_bg2 + 2*D_, buf0, sA2);
    em_kernel<<<ROWS_/4, 128, 0, stream>>>(buf0, sA2, tb_gamma + 2*D_, tb_beta + 2*D_,
                                           em_W1 + 1*D_*D_, em_b1 + 1*D_,
                                           em_W2 + 1*D_*D_, em_b2 + 1*D_, buf1, sE2);
    // Head
    final_kernel<<<ROWS_/4, 256, 0, stream>>>(buf1, sE2, em_gamma + 1*D_, em_beta + 1*D_,
                                              fcf_W1, fcf_b1, fcf_W2, fcf_b2, ebuf);
    maxred_kernel<<<B_, 256, 0, stream>>>(ebuf, out);
}